// Round 9
// baseline (84.469 us; speedup 1.0000x reference)
//
#include <hip/hip_runtime.h>

#define TDIM 4096
#define BDIM 256
#define ADIM 26
#define SDIM 4
#define LCH 16
#define CCH 256
#define NEGF -1e30f
#define LOG2E 1.44269504088896340736f

__device__ __forceinline__ float ex2(float x) { return __builtin_amdgcn_exp2f(x); }
__device__ __forceinline__ float lg2(float x) { return __builtin_amdgcn_logf(x); }

__device__ __forceinline__ float l2se2(float a, float b) {
    float mx = fmaxf(a, b), mn = fminf(a, b);
    return mx + lg2(1.f + ex2(mn - mx));
}
__device__ __forceinline__ float l2se3(float a, float b, float c) {
    float mx = fmaxf(fmaxf(a, b), c);
    float md = __builtin_amdgcn_fmed3f(a, b, c);
    float mn = fminf(fminf(a, b), c);
    return mx + lg2(1.f + ex2(md - mx) + ex2(mn - mx));
}
__device__ __forceinline__ float l2se4(float a, float b, float c, float d) {
    float h1 = fmaxf(a, b), l1 = fminf(a, b);
    float h2 = fmaxf(c, d), l2 = fminf(c, d);
    float mx = fmaxf(h1, h2), s2 = fminf(h1, h2);
    return mx + lg2(1.f + ex2(s2 - mx) + ex2(l1 - mx) + ex2(l2 - mx));
}

struct TransA { float A00, A01, A02, A11, A12, A13, A22, A23, A33; };

__device__ __forceinline__ TransA make_transA(const float* __restrict__ trans) {
    TransA A;
    {
        float l0 = trans[0], l1 = trans[1], l2 = trans[2];
        float m = fmaxf(fmaxf(l0, l1), l2);
        float lz = m + __logf(__expf(l0 - m) + __expf(l1 - m) + __expf(l2 - m));
        A.A00 = (l0 - lz) * LOG2E; A.A01 = (l1 - lz) * LOG2E; A.A02 = (l2 - lz) * LOG2E;
    }
    {
        float l1 = trans[5], l2 = trans[6], l3 = trans[7];
        float m = fmaxf(fmaxf(l1, l2), l3);
        float lz = m + __logf(__expf(l1 - m) + __expf(l2 - m) + __expf(l3 - m));
        A.A11 = (l1 - lz) * LOG2E; A.A12 = (l2 - lz) * LOG2E; A.A13 = (l3 - lz) * LOG2E;
    }
    {
        float l2 = trans[10], l3 = trans[11];
        float m = fmaxf(l2, l3);
        float lz = m + __logf(__expf(l2 - m) + __expf(l3 - m));
        A.A22 = (l2 - lz) * LOG2E; A.A23 = (l3 - lz) * LOG2E;
    }
    A.A33 = 0.f;
    return A;
}

struct UT { float m00, m01, m02, m03, m11, m12, m13, m22, m23, m33; };

// one HMM step composed on the right: M <- M (x) (A + diag-emission e)
__device__ __forceinline__ void fstep(UT& M, const TransA& A, float4 e) {
    float n00 = M.m00 + A.A00 + e.x;
    float n01 = l2se2(M.m00 + A.A01, M.m01 + A.A11) + e.y;
    float n02 = l2se3(M.m00 + A.A02, M.m01 + A.A12, M.m02 + A.A22) + e.z;
    float n03 = l2se3(M.m01 + A.A13, M.m02 + A.A23, M.m03) + e.w;
    float n11 = M.m11 + A.A11 + e.y;
    float n12 = l2se2(M.m11 + A.A12, M.m12 + A.A22) + e.z;
    float n13 = l2se3(M.m11 + A.A13, M.m12 + A.A23, M.m13) + e.w;
    float n22 = M.m22 + A.A22 + e.z;
    float n23 = l2se2(M.m22 + A.A23, M.m23) + e.w;
    float n33 = M.m33 + e.w;
    M.m00 = n00; M.m01 = n01; M.m02 = n02; M.m03 = n03;
    M.m11 = n11; M.m12 = n12; M.m13 = n13; M.m22 = n22; M.m23 = n23; M.m33 = n33;
}

// UT log-semiring matrix product C = A (x) B  (A applied first for row-vec ops)
__device__ __forceinline__ UT ut_compose(const UT& A, const UT& B) {
    UT C;
    C.m00 = A.m00 + B.m00;
    C.m01 = l2se2(A.m00 + B.m01, A.m01 + B.m11);
    C.m02 = l2se3(A.m00 + B.m02, A.m01 + B.m12, A.m02 + B.m22);
    C.m03 = l2se4(A.m00 + B.m03, A.m01 + B.m13, A.m02 + B.m23, A.m03 + B.m33);
    C.m11 = A.m11 + B.m11;
    C.m12 = l2se2(A.m11 + B.m12, A.m12 + B.m22);
    C.m13 = l2se3(A.m11 + B.m13, A.m12 + B.m23, A.m13 + B.m33);
    C.m22 = A.m22 + B.m22;
    C.m23 = l2se2(A.m22 + B.m23, A.m23 + B.m33);
    C.m33 = A.m33 + B.m33;
    return C;
}

__device__ __forceinline__ void ut_renorm(UT& M) {
    float m1 = fmaxf(fmaxf(M.m00, M.m01), fmaxf(M.m02, M.m03));
    float m2 = fmaxf(fmaxf(M.m11, M.m12), fmaxf(M.m13, M.m22));
    float m3 = fmaxf(M.m23, M.m33);
    float mx = fmaxf(fmaxf(m1, m2), m3);
    M.m00 -= mx; M.m01 -= mx; M.m02 -= mx; M.m03 -= mx;
    M.m11 -= mx; M.m12 -= mx; M.m13 -= mx; M.m22 -= mx; M.m23 -= mx; M.m33 -= mx;
}

#define ASTEP(E) do { \
    float4 _e = (E); \
    float n0_ = a0 + A.A00; \
    float n1_ = l2se2(a0 + A.A01, a1 + A.A11); \
    float n2_ = l2se3(a0 + A.A02, a1 + A.A12, a2 + A.A22); \
    float n3_ = l2se3(a1 + A.A13, a2 + A.A23, a3); \
    a0 = n0_ + _e.x; a1 = n1_ + _e.y; a2 = n2_ + _e.z; a3 = n3_ + _e.w; \
    float mm_ = fmaxf(fmaxf(a0, a1), fmaxf(a2, a3)); \
    a0 -= mm_; a1 -= mm_; a2 -= mm_; a3 -= mm_; \
} while (0)

#define BSTEP(E) do { \
    float4 _e = (E); \
    float f0_ = _e.x + b0, f1_ = _e.y + b1, f2_ = _e.z + b2, f3_ = _e.w + b3; \
    float n0_ = l2se3(A.A00 + f0_, A.A01 + f1_, A.A02 + f2_); \
    float n1_ = l2se3(A.A11 + f1_, A.A12 + f2_, A.A13 + f3_); \
    float n2_ = l2se2(A.A22 + f2_, A.A23 + f3_); \
    float n3_ = f3_; \
    float bm_ = fmaxf(fmaxf(n0_, n1_), fmaxf(n2_, n3_)); \
    b0 = n0_ - bm_; b1 = n1_ - bm_; b2 = n2_ - bm_; b3 = n3_ - bm_; \
} while (0)

#define GEMIT(AV, Q) do { \
    float g0_ = (AV).x + b0, g1_ = (AV).y + b1, g2_ = (AV).z + b2, g3_ = (AV).w + b3; \
    float gm_ = fmaxf(fmaxf(g0_, g1_), fmaxf(g2_, g3_)); \
    float q0_ = ex2(g0_ - gm_), q1_ = ex2(g1_ - gm_); \
    float q2_ = ex2(g2_ - gm_), q3_ = ex2(g3_ - gm_); \
    float inv_ = 1.f / (q0_ + q1_ + q2_ + q3_); \
    q0_ *= inv_; q1_ *= inv_; q2_ *= inv_; q3_ *= inv_; \
    vals[(Q)*5 + 0] = fmaf(q0_, wv[0][0], fmaf(q1_, wv[1][0], fmaf(q2_, wv[2][0], q3_ * wv[3][0]))); \
    vals[(Q)*5 + 1] = fmaf(q0_, wv[0][1], fmaf(q1_, wv[1][1], fmaf(q2_, wv[2][1], q3_ * wv[3][1]))); \
    vals[(Q)*5 + 2] = fmaf(q0_, wv[0][2], fmaf(q1_, wv[1][2], fmaf(q2_, wv[2][2], q3_ * wv[3][2]))); \
    vals[(Q)*5 + 3] = fmaf(q0_, wv[0][3], fmaf(q1_, wv[1][3], fmaf(q2_, wv[2][3], q3_ * wv[3][3]))); \
    vals[(Q)*5 + 4] = fmaf(q0_, wv[0][4], fmaf(q1_, wv[1][4], fmaf(q2_, wv[2][4], q3_ * wv[3][4]))); \
} while (0)

// le in LDS: row k = t&15 (stride 257 float4), col = t>>4 -> chunk readers contiguous
#define RDLE(T) sle[(((T) & 15) * 257) + ((T) >> 4)]

__global__ __launch_bounds__(512, 1)
void fused_kernel(const float* __restrict__ x, const float* __restrict__ emit,
                  const float* __restrict__ trans, const float* __restrict__ initl,
                  const float* __restrict__ w, float* __restrict__ out) {
    __shared__ float4 sle[16 * 257];     // 65,792 B
    __shared__ float4 uni[4096];         // 65,536 B: ops (ph1/2) aliased by alpha/beta (ph3)
    __shared__ float vinL[CCH * 4];      // 4,096 B
    __shared__ float wbufL[CCH * 4];     // 4,096 B
    __shared__ float Bmat[SDIM][ADIM];   // 416 B

    float* ops   = reinterpret_cast<float*>(uni);   // 512*10 floats = 20,480 B
    float4* abuf = uni;                             // 256*8 float4 (phase 3)
    float4* bbuf = uni + 2048;                      // 256*8 float4 (phase 3)

    const int tid = threadIdx.x;
    const int bidb = blockIdx.x;

    // ---- emission distributions ----
    if (tid < SDIM) {
        float m = -1e30f;
        #pragma unroll
        for (int a = 0; a < ADIM; ++a) m = fmaxf(m, emit[tid * ADIM + a]);
        float tmp[ADIM];
        float z = 0.f;
        #pragma unroll
        for (int a = 0; a < ADIM; ++a) {
            float e = __expf(emit[tid * ADIM + a] - m);
            tmp[a] = e; z += e;
        }
        float inv = 1.f / z;
        #pragma unroll
        for (int a = 0; a < ADIM; ++a) Bmat[tid][a] = tmp[a] * inv;
    }
    __syncthreads();

    // ---- phase 0: x[bidb] -> le in LDS (pairs of rows, 16B-aligned loads) ----
    #pragma unroll
    for (int i = 0; i < 4; ++i) {
        int p = i * 512 + tid;                       // pair index 0..2047
        const float4* xp = reinterpret_cast<const float4*>(x) + ((size_t)bidb * 2048 + p) * 13;
        float v[52];
        #pragma unroll
        for (int q2 = 0; q2 < 13; ++q2) {
            float4 u = xp[q2];
            v[q2 * 4 + 0] = u.x; v[q2 * 4 + 1] = u.y;
            v[q2 * 4 + 2] = u.z; v[q2 * 4 + 3] = u.w;
        }
        float4 r0, r1;
        {
            float z = 0.f, d0 = 0.f, d1 = 0.f, d2 = 0.f, d3 = 0.f;
            #pragma unroll
            for (int a = 0; a < ADIM; ++a) {
                float e = ex2(v[a] * LOG2E);         // x ~ N(0,1): bounded
                z += e;
                d0 = fmaf(e, Bmat[0][a], d0); d1 = fmaf(e, Bmat[1][a], d1);
                d2 = fmaf(e, Bmat[2][a], d2); d3 = fmaf(e, Bmat[3][a], d3);
            }
            float iz = 1.f / z;
            r0.x = lg2(fmaf(d0, iz, 1e-16f)); r0.y = lg2(fmaf(d1, iz, 1e-16f));
            r0.z = lg2(fmaf(d2, iz, 1e-16f)); r0.w = lg2(fmaf(d3, iz, 1e-16f));
        }
        {
            float z = 0.f, d0 = 0.f, d1 = 0.f, d2 = 0.f, d3 = 0.f;
            #pragma unroll
            for (int a = 0; a < ADIM; ++a) {
                float e = ex2(v[26 + a] * LOG2E);
                z += e;
                d0 = fmaf(e, Bmat[0][a], d0); d1 = fmaf(e, Bmat[1][a], d1);
                d2 = fmaf(e, Bmat[2][a], d2); d3 = fmaf(e, Bmat[3][a], d3);
            }
            float iz = 1.f / z;
            r1.x = lg2(fmaf(d0, iz, 1e-16f)); r1.y = lg2(fmaf(d1, iz, 1e-16f));
            r1.z = lg2(fmaf(d2, iz, 1e-16f)); r1.w = lg2(fmaf(d3, iz, 1e-16f));
        }
        int t = p << 1;
        RDLE(t) = r0;
        RDLE(t + 1) = r1;
    }
    __syncthreads();

    TransA A = make_transA(trans);
    const int cc = tid & 255;
    const int t0 = cc * LCH;
    const bool isB = tid >= 256;      // waves 0-3 forward, waves 4-7 backward

    // ---- phase 1: per-(chunk,dir) operator, L=16 ----
    UT M;
    if (!isB) {
        float4 e0 = RDLE(t0);
        if (cc == 0) {
            M.m00 = e0.x; M.m11 = e0.y; M.m22 = e0.z; M.m33 = e0.w;
            M.m01 = NEGF; M.m02 = NEGF; M.m03 = NEGF; M.m12 = NEGF; M.m13 = NEGF; M.m23 = NEGF;
        } else {
            M.m00 = A.A00 + e0.x; M.m01 = A.A01 + e0.y; M.m02 = A.A02 + e0.z; M.m03 = NEGF;
            M.m11 = A.A11 + e0.y; M.m12 = A.A12 + e0.z; M.m13 = A.A13 + e0.w;
            M.m22 = A.A22 + e0.z; M.m23 = A.A23 + e0.w; M.m33 = e0.w;
        }
        #pragma unroll
        for (int k = 1; k < LCH; ++k) fstep(M, A, RDLE(t0 + k));
    } else {
        M.m00 = 0.f; M.m11 = 0.f; M.m22 = 0.f; M.m33 = 0.f;
        M.m01 = NEGF; M.m02 = NEGF; M.m03 = NEGF; M.m12 = NEGF; M.m13 = NEGF; M.m23 = NEGF;
        int jmax = (cc == CCH - 1) ? (TDIM - 1) : (t0 + LCH);
        #pragma unroll
        for (int k = 0; k < LCH; ++k) {
            int t = t0 + 1 + k;
            if (t <= jmax) fstep(M, A, RDLE(t));
        }
    }
    ut_renorm(M);

    // ---- phase 2: Kogge-Stone scan over operators (fwd prefix / bwd suffix) ----
    const int slot = tid * 10;
    for (int d = 1; d < CCH; d <<= 1) {
        ops[slot + 0] = M.m00; ops[slot + 1] = M.m01; ops[slot + 2] = M.m02; ops[slot + 3] = M.m03;
        ops[slot + 4] = M.m11; ops[slot + 5] = M.m12; ops[slot + 6] = M.m13;
        ops[slot + 7] = M.m22; ops[slot + 8] = M.m23; ops[slot + 9] = M.m33;
        __syncthreads();
        bool act = isB ? (cc + d < CCH) : (cc >= d);
        UT Nn;
        if (act) {
            int ns = (isB ? (tid + d) : (tid - d)) * 10;
            Nn.m00 = ops[ns + 0]; Nn.m01 = ops[ns + 1]; Nn.m02 = ops[ns + 2]; Nn.m03 = ops[ns + 3];
            Nn.m11 = ops[ns + 4]; Nn.m12 = ops[ns + 5]; Nn.m13 = ops[ns + 6];
            Nn.m22 = ops[ns + 7]; Nn.m23 = ops[ns + 8]; Nn.m33 = ops[ns + 9];
        }
        __syncthreads();
        if (act) {
            M = isB ? ut_compose(M, Nn) : ut_compose(Nn, M);
            ut_renorm(M);
        }
    }
    // final exchange for exclusive-prefix read
    ops[slot + 0] = M.m00; ops[slot + 1] = M.m01; ops[slot + 2] = M.m02; ops[slot + 3] = M.m03;
    ops[slot + 4] = M.m11; ops[slot + 5] = M.m12; ops[slot + 6] = M.m13;
    ops[slot + 7] = M.m22; ops[slot + 8] = M.m23; ops[slot + 9] = M.m33;
    __syncthreads();

    if (!isB) {
        // vin[cc] = init (x) Q_{cc-1}
        float i0 = initl[0], i1 = initl[1], i2 = initl[2], i3 = initl[3];
        float mI = fmaxf(fmaxf(i0, i1), fmaxf(i2, i3));
        float lz = mI + __logf(__expf(i0 - mI) + __expf(i1 - mI) + __expf(i2 - mI) + __expf(i3 - mI));
        i0 = (i0 - lz) * LOG2E; i1 = (i1 - lz) * LOG2E; i2 = (i2 - lz) * LOG2E; i3 = (i3 - lz) * LOG2E;
        float v0, v1, v2, v3;
        if (cc == 0) {
            v0 = i0; v1 = i1; v2 = i2; v3 = i3;
        } else {
            int ns = (tid - 1) * 10;
            float q00 = ops[ns + 0], q01 = ops[ns + 1], q02 = ops[ns + 2], q03 = ops[ns + 3];
            float q11 = ops[ns + 4], q12 = ops[ns + 5], q13 = ops[ns + 6];
            float q22 = ops[ns + 7], q23 = ops[ns + 8], q33 = ops[ns + 9];
            v0 = i0 + q00;
            v1 = l2se2(i0 + q01, i1 + q11);
            v2 = l2se3(i0 + q02, i1 + q12, i2 + q22);
            v3 = l2se4(i0 + q03, i1 + q13, i2 + q23, i3 + q33);
            float mm = fmaxf(fmaxf(v0, v1), fmaxf(v2, v3));
            v0 -= mm; v1 -= mm; v2 -= mm; v3 -= mm;
        }
        vinL[cc * 4 + 0] = v0; vinL[cc * 4 + 1] = v1;
        vinL[cc * 4 + 2] = v2; vinL[cc * 4 + 3] = v3;
    } else {
        // u_cc = row-lse(R_cc); store as boundary for chunk cc-1
        float u0 = l2se4(M.m00, M.m01, M.m02, M.m03);
        float u1 = l2se3(M.m11, M.m12, M.m13);
        float u2 = l2se2(M.m22, M.m23);
        float u3 = M.m33;
        float mm = fmaxf(fmaxf(u0, u1), fmaxf(u2, u3));
        u0 -= mm; u1 -= mm; u2 -= mm; u3 -= mm;
        if (cc >= 1) {
            wbufL[(cc - 1) * 4 + 0] = u0; wbufL[(cc - 1) * 4 + 1] = u1;
            wbufL[(cc - 1) * 4 + 2] = u2; wbufL[(cc - 1) * 4 + 3] = u3;
        }
        if (cc == CCH - 1) {
            wbufL[(CCH - 1) * 4 + 0] = 0.f; wbufL[(CCH - 1) * 4 + 1] = 0.f;
            wbufL[(CCH - 1) * 4 + 2] = 0.f; wbufL[(CCH - 1) * 4 + 3] = 0.f;
        }
    }
    __syncthreads();

    // ---- phase 3: replay + gamma.w emit ----
    float wv[SDIM][5];
    #pragma unroll
    for (int s = 0; s < SDIM; ++s)
        #pragma unroll
        for (int o = 0; o < 5; ++o) wv[s][o] = w[s * 5 + o];

    float* opb = out + (size_t)bidb * TDIM * 5;
    float vals[20];
    float a0, a1, a2, a3, b0, b1, b2, b3;

    if (!isB) {
        a0 = vinL[cc * 4 + 0]; a1 = vinL[cc * 4 + 1];
        a2 = vinL[cc * 4 + 2]; a3 = vinL[cc * 4 + 3];
        if (cc == 0) {
            float4 e = RDLE(0);
            a0 += e.x; a1 += e.y; a2 += e.z; a3 += e.w;
            float mm = fmaxf(fmaxf(a0, a1), fmaxf(a2, a3));
            a0 -= mm; a1 -= mm; a2 -= mm; a3 -= mm;
        } else {
            ASTEP(RDLE(t0));
        }
        abuf[cc * 8 + 0] = make_float4(a0, a1, a2, a3);
        #pragma unroll
        for (int k = 1; k < 8; ++k) {
            ASTEP(RDLE(t0 + k));
            abuf[cc * 8 + k] = make_float4(a0, a1, a2, a3);
        }
    } else {
        b0 = wbufL[cc * 4 + 0]; b1 = wbufL[cc * 4 + 1];
        b2 = wbufL[cc * 4 + 2]; b3 = wbufL[cc * 4 + 3];
        bool lastc = (cc == CCH - 1);
        #pragma unroll
        for (int k = 15; k >= 8; --k) {
            if (!(lastc && k == 15)) BSTEP(RDLE(t0 + 1 + k));
            bbuf[cc * 8 + (k - 8)] = make_float4(b0, b1, b2, b3);
        }
    }
    __syncthreads();

    if (!isB) {
        #pragma unroll
        for (int g = 2; g < 4; ++g) {
            #pragma unroll
            for (int q = 0; q < 4; ++q) {
                int k = g * 4 + q;
                ASTEP(RDLE(t0 + k));
                float4 bv = bbuf[cc * 8 + (k - 8)];
                b0 = bv.x; b1 = bv.y; b2 = bv.z; b3 = bv.w;
                float4 av = make_float4(a0, a1, a2, a3);
                GEMIT(av, q);
            }
            float4* vo = reinterpret_cast<float4*>(opb + (size_t)(t0 + g * 4) * 5);
            vo[0] = make_float4(vals[0],  vals[1],  vals[2],  vals[3]);
            vo[1] = make_float4(vals[4],  vals[5],  vals[6],  vals[7]);
            vo[2] = make_float4(vals[8],  vals[9],  vals[10], vals[11]);
            vo[3] = make_float4(vals[12], vals[13], vals[14], vals[15]);
            vo[4] = make_float4(vals[16], vals[17], vals[18], vals[19]);
        }
    } else {
        #pragma unroll
        for (int g = 1; g >= 0; --g) {
            #pragma unroll
            for (int q = 3; q >= 0; --q) {
                int k = g * 4 + q;
                BSTEP(RDLE(t0 + 1 + k));
                float4 av = abuf[cc * 8 + k];
                GEMIT(av, q);
            }
            float4* vo = reinterpret_cast<float4*>(opb + (size_t)(t0 + g * 4) * 5);
            vo[0] = make_float4(vals[0],  vals[1],  vals[2],  vals[3]);
            vo[1] = make_float4(vals[4],  vals[5],  vals[6],  vals[7]);
            vo[2] = make_float4(vals[8],  vals[9],  vals[10], vals[11]);
            vo[3] = make_float4(vals[12], vals[13], vals[14], vals[15]);
            vo[4] = make_float4(vals[16], vals[17], vals[18], vals[19]);
        }
    }
}

extern "C" void kernel_launch(void* const* d_in, const int* in_sizes, int n_in,
                              void* d_out, int out_size, void* d_ws, size_t ws_size,
                              hipStream_t stream) {
    const float* x     = (const float*)d_in[0];
    const float* emit  = (const float*)d_in[1];
    const float* trans = (const float*)d_in[2];
    const float* initl = (const float*)d_in[3];
    const float* w     = (const float*)d_in[4];
    float* out = (float*)d_out;

    hipLaunchKernelGGL(fused_kernel, dim3(BDIM), dim3(512), 0, stream,
                       x, emit, trans, initl, w, out);
}